// Round 12
// baseline (87.014 us; speedup 1.0000x reference)
//
#include <hip/hip_runtime.h>
#include <math.h>

#define B_ 8
#define BIGF 3.4e38f

// ws layout (16-B aligned base):
//   packT  : B_*N float4 {x,y,z,|t|^2}
//   packS  : B_*M float4 {x,y,z,|s|^2}
//   minarr : B_*N uint rowmin (per-target min d^2, uint-ordered floats)
//            followed by B_*M uint colmin (per-source min d^2)
// R8 structure; single change: QPT 8->16 (DS/VALU 86% -> 43%).

__global__ __launch_bounds__(256) void pack_kernel(
    const float* __restrict__ tar, const float* __restrict__ src,
    float4* __restrict__ packT, float4* __restrict__ packS,
    unsigned int* __restrict__ minarr, float* __restrict__ outp,
    int N, int M)
{
    const int i = blockIdx.x * 256 + threadIdx.x;
    const int nT = B_ * N, nS = B_ * M;
    if (i < nT) {
        float x = tar[3 * i], y = tar[3 * i + 1], z = tar[3 * i + 2];
        packT[i] = make_float4(x, y, z, fmaf(x, x, fmaf(y, y, z * z)));
    } else if (i < nT + nS) {
        int j = i - nT;
        float x = src[3 * j], y = src[3 * j + 1], z = src[3 * j + 2];
        packS[j] = make_float4(x, y, z, fmaf(x, x, fmaf(y, y, z * z)));
    }
    if (i < nT + nS) minarr[i] = 0x7F800000u;  // +inf
    if (i < 3) outp[i] = 0.f;
}

// Two-pass structure (both dirs via blockIdx.z), LDS-staged float4 refs.
// QPT=16, CHUNK=128: per j-pair iter a wave issues 2 ds_read_b128 (~24 DS
// cyc) against 112 VALU insts — DS pipe demand 43% of VALU (QPT=8 was 86%,
// nearly co-bound: the stubborn ~2x-over-VALU-floor across R2-R10).
// grid = 1 x 32 x 16 = 512 blocks (2/CU, 8 waves/CU); 16 independent FMA
// chains per ref point cover DS latency at 2 waves/SIMD.
// Atomics unchanged vs R8: gy=32 -> 2.1M distributed atomicMin.
// d^2 = |q|^2 + (|p|^2 - 2 q.p); |q|^2 added after the min (monotone).
template <int QPT, int CHUNK>
__global__ __launch_bounds__(256) void minsq_kernel(
    const float4* __restrict__ packT, const float4* __restrict__ packS,
    unsigned int* __restrict__ minarr, int N, int M)
{
    const int z   = blockIdx.z;
    const int dir = (z >= B_) ? 1 : 0;
    const int b   = dir ? (z - B_) : z;
    const float4* __restrict__ qry = dir ? packS : packT;
    const float4* __restrict__ pts = dir ? packT : packS;
    const int K = dir ? M : N;   // query count
    const int L = dir ? N : M;   // reference count
    unsigned int* __restrict__ out =
        minarr + (dir ? (size_t)B_ * N : (size_t)0) + (size_t)b * K;

    const int base = blockIdx.y * CHUNK;
    if (base >= L) return;
    const int cnt = min(CHUNK, L - base);

    __shared__ float4 sp[CHUNK];
    const float4* __restrict__ psrc = pts + (size_t)b * L + base;
    const int t = threadIdx.x;
    for (int i = t; i < cnt; i += 256) sp[i] = psrc[i];
    __syncthreads();

    const int qbase = blockIdx.x * (256 * QPT);
    float qx2[QPT], qy2[QPT], qz2[QPT], qw[QPT], mn[QPT];
#pragma unroll
    for (int k = 0; k < QPT; ++k) {
        int qi = qbase + k * 256 + t;
        if (qi < K) {
            float4 q = qry[(size_t)b * K + qi];
            qx2[k] = -2.f * q.x; qy2[k] = -2.f * q.y; qz2[k] = -2.f * q.z;
            qw[k] = q.w;
        } else {
            qx2[k] = 0.f; qy2[k] = 0.f; qz2[k] = 0.f; qw[k] = 0.f;
        }
        mn[k] = BIGF;
    }

    if (cnt == CHUNK) {
#pragma unroll 2
        for (int j = 0; j < CHUNK; j += 2) {
            float4 p0 = sp[j];
            float4 p1 = sp[j + 1];
#pragma unroll
            for (int k = 0; k < QPT; ++k) {
                float d0 = fmaf(qx2[k], p0.x, fmaf(qy2[k], p0.y,
                           fmaf(qz2[k], p0.z, p0.w)));
                float d1 = fmaf(qx2[k], p1.x, fmaf(qy2[k], p1.y,
                           fmaf(qz2[k], p1.z, p1.w)));
                mn[k] = fminf(mn[k], fminf(d0, d1));   // v_min3_f32
            }
        }
    } else {
        int j = 0;
        for (; j + 1 < cnt; j += 2) {
            float4 p0 = sp[j];
            float4 p1 = sp[j + 1];
#pragma unroll
            for (int k = 0; k < QPT; ++k) {
                float d0 = fmaf(qx2[k], p0.x, fmaf(qy2[k], p0.y,
                           fmaf(qz2[k], p0.z, p0.w)));
                float d1 = fmaf(qx2[k], p1.x, fmaf(qy2[k], p1.y,
                           fmaf(qz2[k], p1.z, p1.w)));
                mn[k] = fminf(mn[k], fminf(d0, d1));
            }
        }
        if (j < cnt) {
            float4 p0 = sp[j];
#pragma unroll
            for (int k = 0; k < QPT; ++k) {
                float d0 = fmaf(qx2[k], p0.x, fmaf(qy2[k], p0.y,
                           fmaf(qz2[k], p0.z, p0.w)));
                mn[k] = fminf(mn[k], d0);
            }
        }
    }

#pragma unroll
    for (int k = 0; k < QPT; ++k) {
        int qi = qbase + k * 256 + t;
        if (qi < K) {
            float d2 = fmaxf(mn[k] + qw[k], 0.f);  // clamp roundoff negatives
            atomicMin(&out[qi], __float_as_uint(d2));
        }
    }
}

// Merged reduce+finalize: 32 blocks stripe-sum sqrt of both regions, then 3
// scaled atomicAdds into d_out (zeroed by pack_kernel). 96 same-line atomics.
__global__ __launch_bounds__(256) void reduce_kernel(
    const unsigned int* __restrict__ minarr, float* __restrict__ outp,
    int N, int M)
{
    const int nt = B_ * N, ns = B_ * M;
    const int gid = blockIdx.x * 256 + threadIdx.x;
    const int stride = gridDim.x * 256;
    float s_t = 0.f, s_s = 0.f;
    for (int i = gid; i < nt; i += stride)
        s_t += sqrtf(__uint_as_float(minarr[i]));
    for (int i = gid; i < ns; i += stride)
        s_s += sqrtf(__uint_as_float(minarr[nt + i]));
#pragma unroll
    for (int off = 32; off > 0; off >>= 1) {
        s_t += __shfl_down(s_t, off);
        s_s += __shfl_down(s_s, off);
    }
    __shared__ float rt[4], rs[4];
    const int wid = threadIdx.x >> 6, lid = threadIdx.x & 63;
    if (lid == 0) { rt[wid] = s_t; rs[wid] = s_s; }
    __syncthreads();
    if (threadIdx.x == 0) {
        float ct = (rt[0] + rt[1] + rt[2] + rt[3]) / (float)nt;  // complete
        float ac = (rs[0] + rs[1] + rs[2] + rs[3]) / (float)ns;  // accuracy
        atomicAdd(&outp[0], ac);
        atomicAdd(&outp[1], ct);
        atomicAdd(&outp[2], 0.5f * (ac + ct));
    }
}

extern "C" void kernel_launch(void* const* d_in, const int* in_sizes, int n_in,
                              void* d_out, int out_size, void* d_ws, size_t ws_size,
                              hipStream_t stream) {
    const float* tar = (const float*)d_in[0];
    const float* src = (const float*)d_in[1];
    const int N = in_sizes[0] / (B_ * 3);
    const int M = in_sizes[1] / (B_ * 3);

    float4* packT = (float4*)d_ws;
    float4* packS = packT + (size_t)B_ * N;
    unsigned int* minarr = (unsigned int*)(packS + (size_t)B_ * M);
    float* outp = (float*)d_out;

    pack_kernel<<<dim3((B_ * (N + M) + 255) / 256), dim3(256), 0, stream>>>(
        tar, src, packT, packS, minarr, outp, N, M);

    constexpr int QPT = 16, CHUNK = 128;
    const int KL = (N > M) ? N : M;
    const int gx = (KL + 256 * QPT - 1) / (256 * QPT);   // 1
    const int gy = (KL + CHUNK - 1) / CHUNK;             // 32
    dim3 grid(gx, gy, 2 * B_);                            // 512 blocks
    minsq_kernel<QPT, CHUNK><<<grid, dim3(256), 0, stream>>>(
        packT, packS, minarr, N, M);

    reduce_kernel<<<dim3(32), dim3(256), 0, stream>>>(minarr, outp, N, M);
}

// Round 13
// 84.091 us; speedup vs baseline: 1.0348x; 1.0348x over previous
//
#include <hip/hip_runtime.h>
#include <math.h>

#define B_ 8
#define BIGF 3.4e38f

// FINAL: R8 configuration (measured best, 83.5/84.6 us; every structural
// deviation tested in R2-R12 regressed).
// ws layout (16-B aligned base):
//   packT  : B_*N float4 {x,y,z,|t|^2}
//   packS  : B_*M float4 {x,y,z,|s|^2}
//   minarr : B_*N uint rowmin (per-target min d^2, uint-ordered floats)
//            followed by B_*M uint colmin (per-source min d^2)

// Pack points to float4, init min arrays to +inf, zero d_out. One node.
__global__ __launch_bounds__(256) void pack_kernel(
    const float* __restrict__ tar, const float* __restrict__ src,
    float4* __restrict__ packT, float4* __restrict__ packS,
    unsigned int* __restrict__ minarr, float* __restrict__ outp,
    int N, int M)
{
    const int i = blockIdx.x * 256 + threadIdx.x;
    const int nT = B_ * N, nS = B_ * M;
    if (i < nT) {
        float x = tar[3 * i], y = tar[3 * i + 1], z = tar[3 * i + 2];
        packT[i] = make_float4(x, y, z, fmaf(x, x, fmaf(y, y, z * z)));
    } else if (i < nT + nS) {
        int j = i - nT;
        float x = src[3 * j], y = src[3 * j + 1], z = src[3 * j + 2];
        packS[j] = make_float4(x, y, z, fmaf(x, x, fmaf(y, y, z * z)));
    }
    if (i < nT + nS) minarr[i] = 0x7F800000u;  // +inf
    if (i < 3) outp[i] = 0.f;
}

// Two-pass structure (both dirs via blockIdx.z), LDS-staged float4 refs.
// QPT=8, CHUNK=128, grid 2x32x16 = 1024 blocks (4/CU, 16 waves/CU).
// d^2 = |q|^2 + (|p|^2 - 2 q.p); |q|^2 added after the min (monotone).
// Cross-block combine: distributed uint atomicMin (d^2 clamped >= 0 so
// uint order == float order); 2.1M distributed atomics (proven OK scale).
template <int QPT, int CHUNK>
__global__ __launch_bounds__(256) void minsq_kernel(
    const float4* __restrict__ packT, const float4* __restrict__ packS,
    unsigned int* __restrict__ minarr, int N, int M)
{
    const int z   = blockIdx.z;
    const int dir = (z >= B_) ? 1 : 0;
    const int b   = dir ? (z - B_) : z;
    const float4* __restrict__ qry = dir ? packS : packT;
    const float4* __restrict__ pts = dir ? packT : packS;
    const int K = dir ? M : N;   // query count
    const int L = dir ? N : M;   // reference count
    unsigned int* __restrict__ out =
        minarr + (dir ? (size_t)B_ * N : (size_t)0) + (size_t)b * K;

    const int base = blockIdx.y * CHUNK;
    if (base >= L) return;
    const int cnt = min(CHUNK, L - base);

    __shared__ float4 sp[CHUNK];
    const float4* __restrict__ psrc = pts + (size_t)b * L + base;
    const int t = threadIdx.x;
    for (int i = t; i < cnt; i += 256) sp[i] = psrc[i];
    __syncthreads();

    const int qbase = blockIdx.x * (256 * QPT);
    float qx2[QPT], qy2[QPT], qz2[QPT], qw[QPT], mn[QPT];
#pragma unroll
    for (int k = 0; k < QPT; ++k) {
        int qi = qbase + k * 256 + t;
        if (qi < K) {
            float4 q = qry[(size_t)b * K + qi];
            qx2[k] = -2.f * q.x; qy2[k] = -2.f * q.y; qz2[k] = -2.f * q.z;
            qw[k] = q.w;
        } else {
            qx2[k] = 0.f; qy2[k] = 0.f; qz2[k] = 0.f; qw[k] = 0.f;
        }
        mn[k] = BIGF;
    }

    if (cnt == CHUNK) {
#pragma unroll 4
        for (int j = 0; j < CHUNK; j += 2) {
            float4 p0 = sp[j];
            float4 p1 = sp[j + 1];
#pragma unroll
            for (int k = 0; k < QPT; ++k) {
                float d0 = fmaf(qx2[k], p0.x, fmaf(qy2[k], p0.y,
                           fmaf(qz2[k], p0.z, p0.w)));
                float d1 = fmaf(qx2[k], p1.x, fmaf(qy2[k], p1.y,
                           fmaf(qz2[k], p1.z, p1.w)));
                mn[k] = fminf(mn[k], fminf(d0, d1));   // v_min3_f32
            }
        }
    } else {
        int j = 0;
        for (; j + 1 < cnt; j += 2) {
            float4 p0 = sp[j];
            float4 p1 = sp[j + 1];
#pragma unroll
            for (int k = 0; k < QPT; ++k) {
                float d0 = fmaf(qx2[k], p0.x, fmaf(qy2[k], p0.y,
                           fmaf(qz2[k], p0.z, p0.w)));
                float d1 = fmaf(qx2[k], p1.x, fmaf(qy2[k], p1.y,
                           fmaf(qz2[k], p1.z, p1.w)));
                mn[k] = fminf(mn[k], fminf(d0, d1));
            }
        }
        if (j < cnt) {
            float4 p0 = sp[j];
#pragma unroll
            for (int k = 0; k < QPT; ++k) {
                float d0 = fmaf(qx2[k], p0.x, fmaf(qy2[k], p0.y,
                           fmaf(qz2[k], p0.z, p0.w)));
                mn[k] = fminf(mn[k], d0);
            }
        }
    }

#pragma unroll
    for (int k = 0; k < QPT; ++k) {
        int qi = qbase + k * 256 + t;
        if (qi < K) {
            float d2 = fmaxf(mn[k] + qw[k], 0.f);  // clamp roundoff negatives
            atomicMin(&out[qi], __float_as_uint(d2));
        }
    }
}

// Merged reduce+finalize: 32 blocks stripe-sum sqrt of both regions, then 3
// scaled atomicAdds into d_out (zeroed by pack_kernel). 96 same-line atomics.
__global__ __launch_bounds__(256) void reduce_kernel(
    const unsigned int* __restrict__ minarr, float* __restrict__ outp,
    int N, int M)
{
    const int nt = B_ * N, ns = B_ * M;
    const int gid = blockIdx.x * 256 + threadIdx.x;
    const int stride = gridDim.x * 256;
    float s_t = 0.f, s_s = 0.f;
    for (int i = gid; i < nt; i += stride)
        s_t += sqrtf(__uint_as_float(minarr[i]));
    for (int i = gid; i < ns; i += stride)
        s_s += sqrtf(__uint_as_float(minarr[nt + i]));
#pragma unroll
    for (int off = 32; off > 0; off >>= 1) {
        s_t += __shfl_down(s_t, off);
        s_s += __shfl_down(s_s, off);
    }
    __shared__ float rt[4], rs[4];
    const int wid = threadIdx.x >> 6, lid = threadIdx.x & 63;
    if (lid == 0) { rt[wid] = s_t; rs[wid] = s_s; }
    __syncthreads();
    if (threadIdx.x == 0) {
        float ct = (rt[0] + rt[1] + rt[2] + rt[3]) / (float)nt;  // complete
        float ac = (rs[0] + rs[1] + rs[2] + rs[3]) / (float)ns;  // accuracy
        atomicAdd(&outp[0], ac);
        atomicAdd(&outp[1], ct);
        atomicAdd(&outp[2], 0.5f * (ac + ct));
    }
}

extern "C" void kernel_launch(void* const* d_in, const int* in_sizes, int n_in,
                              void* d_out, int out_size, void* d_ws, size_t ws_size,
                              hipStream_t stream) {
    const float* tar = (const float*)d_in[0];
    const float* src = (const float*)d_in[1];
    const int N = in_sizes[0] / (B_ * 3);
    const int M = in_sizes[1] / (B_ * 3);

    float4* packT = (float4*)d_ws;
    float4* packS = packT + (size_t)B_ * N;
    unsigned int* minarr = (unsigned int*)(packS + (size_t)B_ * M);
    float* outp = (float*)d_out;

    pack_kernel<<<dim3((B_ * (N + M) + 255) / 256), dim3(256), 0, stream>>>(
        tar, src, packT, packS, minarr, outp, N, M);

    constexpr int QPT = 8, CHUNK = 128;
    const int KL = (N > M) ? N : M;
    const int gx = (KL + 256 * QPT - 1) / (256 * QPT);   // 2
    const int gy = (KL + CHUNK - 1) / CHUNK;             // 32
    dim3 grid(gx, gy, 2 * B_);                            // 1024 blocks
    minsq_kernel<QPT, CHUNK><<<grid, dim3(256), 0, stream>>>(
        packT, packS, minarr, N, M);

    reduce_kernel<<<dim3(32), dim3(256), 0, stream>>>(minarr, outp, N, M);
}